// Round 6
// baseline (1920.639 us; speedup 1.0000x reference)
//
#include <hip/hip_runtime.h>

// LSTMencoder: 2-layer biLSTM, B=256, T=2048, H=32 (4H=128 gates), in=32/64.
//
// R6: same pipeline as R5 (chunked xg gemm, serial rec, NEXT chunk's gemm
// fused into the rec launch, ping-pong xg buffers, C=512) but the fused
// kernel is now HOMOGENEOUS 64-thread blocks with __launch_bounds__(64,1):
// R5's fused kernel compiled at VGPR_Count=48 (launch_bounds(256,2) regalloc
// sacrificed the rec branch -> weights spilled to scratch, 234us vs 150us
// standalone). gemm body re-tiled to 64 threads (16 t x 1 dir x 64 gates).
// rec body = R3/R5-verified single-chain version, unchanged.
// Path B fallback: original harness-verified fused kernel (tiny ws).

#define T_LEN 2048
#define BATCH 256
#define HID   32
#define PF    8
#define REC_BLOCKS 512

__device__ __forceinline__ float frcp(float x) { return __builtin_amdgcn_rcpf(x); }
__device__ __forceinline__ float rdlane(float v, int k) {
    return __int_as_float(__builtin_amdgcn_readlane(__float_as_int(v), k));
}

template<int N>
__device__ __forceinline__ void load_row(float* dst, const float* __restrict__ src) {
#pragma unroll
    for (int i = 0; i < N / 4; ++i) {
        float4 v = reinterpret_cast<const float4*>(src)[i];
        dst[4*i+0] = v.x; dst[4*i+1] = v.y; dst[4*i+2] = v.z; dst[4*i+3] = v.w;
    }
}

// ===================== gemm body, 64-thread tile =====================
// gb decomposition: b = gb & 255; t_idx = gb >> 8; tile = t_idx >> 2;
// d = (t_idx >> 1) & 1; ghalf = t_idx & 1. Block covers 16 timesteps x one
// dir x 64 gates (g = ghalf*64 + lane). Same verified staging/broadcast/
// write logic as the R2 gemm, quartered.
template<int LAYER>
__device__ __forceinline__ void gemm_body64(
        int gb,
        const float* __restrict__ OS, const float* __restrict__ IS,
        const float* __restrict__ h1,
        const float* __restrict__ Wih, const float* __restrict__ bih,
        const float* __restrict__ bhh, float* __restrict__ xg,
        int t_base, int C)
{
    constexpr int F  = (LAYER == 0) ? 32 : 64;
    constexpr int TT = 16;
    __shared__ float xs[TT][F];
    const int l     = threadIdx.x;          // 0..63
    const int b     = gb & (BATCH - 1);
    const int t_idx = gb >> 8;
    const int lt0   = (t_idx >> 2) * TT;
    const int d     = (t_idx >> 1) & 1;
    const int g     = (t_idx & 1) * 64 + l;

    // stage x tile for this dir into LDS (coalesced in f)
    constexpr int TOT = TT * F;             // 512 (L0) / 1024 (L1)
#pragma unroll
    for (int rep = 0; rep < TOT / 64; ++rep) {
        int flat = rep * 64 + l;
        int tt = flat / F, f = flat % F;
        int tl = t_base + lt0 + tt;
        int te = d ? (T_LEN - 1 - tl) : tl;
        float v;
        if (LAYER == 0) {
            v = (f < 16) ? OS[((size_t)b * T_LEN + te) * 16 + f]
                         : IS[((size_t)b * T_LEN + (T_LEN - 1 - te)) * 16 + (f - 16)];
        } else {
            v = h1[((size_t)te * BATCH + b) * 64 + f];
        }
        xs[tt][f] = v;
    }

    float w[F];
    load_row<F>(w, Wih + ((size_t)d * 128 + g) * F);
    const float bias = bih[d * 128 + g] + bhh[d * 128 + g];
    __syncthreads();

#pragma unroll
    for (int tt = 0; tt < TT; ++tt) {
        float a0 = bias, a1 = 0.f, a2 = 0.f, a3 = 0.f;
#pragma unroll
        for (int j = 0; j < F / 4; ++j) {
            float4 x = reinterpret_cast<const float4*>(xs[tt])[j];
            a0 = fmaf(x.x, w[4*j+0], a0);
            a1 = fmaf(x.y, w[4*j+1], a1);
            a2 = fmaf(x.z, w[4*j+2], a2);
            a3 = fmaf(x.w, w[4*j+3], a3);
        }
        xg[(((size_t)d * C + (lt0 + tt)) * BATCH + b) * 128 + g] = (a0 + a1) + (a2 + a3);
    }
}

// ===================== rec body (R3/R5-verified single-chain) =====================
template<int LAYER>
__device__ __forceinline__ void rec_body(
        int rb, const float* __restrict__ xg, const float* __restrict__ Whh,
        float* __restrict__ outp, float* __restrict__ state,
        int t_base, int C)
{
    const int l   = threadIdx.x;     // 0..63
    const int b   = rb & (BATCH - 1);
    const int d   = rb >> 8;         // 0 fwd, 1 bwd
    const bool lo = (l < HID);
    const int chain = d * BATCH + b;
    const int xl  = (l + 32) & 63;   // swap partner

    const float mB = lo ? -2.f : -1.f;
    const float kM = lo ?  2.f :  1.f;
    const float kA = lo ? -1.f :  0.f;

    float wa[HID], wb[HID];
    load_row<HID>(wa, Whh + ((size_t)d * 128 + l) * HID);
    load_row<HID>(wb, Whh + ((size_t)d * 128 + 64 + l) * HID);

    float c = 0.f, hj = 0.f;
    if (t_base > 0 && lo) {
        c  = state[(size_t)chain * 64 + l];
        hj = state[(size_t)chain * 64 + 32 + l];
    }
    float h[HID];
#pragma unroll
    for (int k = 0; k < HID; ++k) h[k] = rdlane(hj, k);

    const size_t STRIDE = (size_t)BATCH * 128;
    const float* xp = xg + (size_t)d * C * STRIDE + (size_t)b * 128;
    const float* pf = xp + (size_t)PF * STRIDE;

    float ra[PF], rb_[PF];
#pragma unroll
    for (int u = 0; u < PF; ++u) {
        ra[u]  = xp[(size_t)u * STRIDE + l];
        rb_[u] = xp[(size_t)u * STRIDE + 64 + l];
    }

    const int te0 = d ? (T_LEN - 1 - t_base) : t_base;
    float* op;
    ptrdiff_t ostep;
    if constexpr (LAYER == 0) {
        op = outp + ((size_t)te0 * BATCH + b) * 64 + d * HID + l;
        ostep = d ? -(ptrdiff_t)(BATCH * 64) : (ptrdiff_t)(BATCH * 64);
    } else {
        op = outp + ((size_t)b * T_LEN + te0) * 64 + d * HID + l;
        ostep = d ? (ptrdiff_t)-64 : (ptrdiff_t)64;
    }

#pragma unroll 1
    for (int tb = 0; tb < C; tb += PF) {
#pragma unroll
        for (int k = 0; k < HID; k += 4)
            asm volatile("" : "+v"(wa[k]), "+v"(wa[k+1]), "+v"(wa[k+2]), "+v"(wa[k+3]));
#pragma unroll
        for (int k = 0; k < HID; k += 4)
            asm volatile("" : "+v"(wb[k]), "+v"(wb[k+1]), "+v"(wb[k+2]), "+v"(wb[k+3]));

#pragma unroll
        for (int u = 0; u < PF; ++u) {
            const float xa = ra[u], xb = rb_[u];
            ra[u]  = pf[l];
            rb_[u] = pf[64 + l];
            pf += STRIDE;

            float a0 = xa, a1 = 0.f, a2 = 0.f, a3 = 0.f;
            float b0 = xb, b1 = 0.f, b2 = 0.f, b3 = 0.f;
#pragma unroll
            for (int k = 0; k < 8; ++k) {
                a0 = fmaf(h[k],      wa[k],      a0);
                a1 = fmaf(h[k + 8],  wa[k + 8],  a1);
                a2 = fmaf(h[k + 16], wa[k + 16], a2);
                a3 = fmaf(h[k + 24], wa[k + 24], a3);
                b0 = fmaf(h[k],      wb[k],      b0);
                b1 = fmaf(h[k + 8],  wb[k + 8],  b1);
                b2 = fmaf(h[k + 16], wb[k + 16], b2);
                b3 = fmaf(h[k + 24], wb[k + 24], b3);
            }
            const float accA = (a0 + a1) + (a2 + a3);
            const float accB = (b0 + b1) + (b2 + b3);

            const float sA = frcp(1.f + __expf(-accA));
            const float rB = frcp(1.f + __expf(mB * accB));
            const float sB = fmaf(kM, rB, kA);
            const float sf = __shfl(sA, xl);
            const float so = __shfl(sB, xl);
            c = fmaf(sf, c, sA * sB);
            const float tc = fmaf(2.f, frcp(1.f + __expf(-2.f * c)), -1.f);
            hj = so * tc;
            if (lo) *op = hj;
            op += ostep;
#pragma unroll
            for (int k = 0; k < HID; ++k) h[k] = rdlane(hj, k);
        }
    }

    if (lo) {
        state[(size_t)chain * 64 + l]      = c;
        state[(size_t)chain * 64 + 32 + l] = hj;
    }
}

// ===================== kernels =====================
template<int LAYER>
__global__ __launch_bounds__(64) void xg_gemm_k(
        const float* __restrict__ OS, const float* __restrict__ IS,
        const float* __restrict__ h1,
        const float* __restrict__ Wih, const float* __restrict__ bih,
        const float* __restrict__ bhh, float* __restrict__ xg,
        int t_base, int C)
{
    gemm_body64<LAYER>(blockIdx.x, OS, IS, h1, Wih, bih, bhh, xg, t_base, C);
}

template<int LAYER>
__global__ __launch_bounds__(64, 1) void lstm_rec_k(
        const float* __restrict__ xg, const float* __restrict__ Whh,
        float* __restrict__ outp, float* __restrict__ state,
        int t_base, int C)
{
    rec_body<LAYER>(blockIdx.x, xg, Whh, outp, state, t_base, C);
}

// rec for chunk i (xg_rec) + gemm for chunk i+1 (xg_next) in ONE launch.
// Homogeneous 64-thread blocks; blocks [0,512) = rec, rest = gemm.
template<int LAYER>
__global__ __launch_bounds__(64, 1) void fused_rec_gemm(
        const float* __restrict__ OS, const float* __restrict__ IS,
        const float* __restrict__ h1,
        const float* __restrict__ Wih, const float* __restrict__ bih,
        const float* __restrict__ bhh,
        const float* __restrict__ xg_rec, float* __restrict__ xg_next,
        const float* __restrict__ Whh,
        float* __restrict__ outp, float* __restrict__ state,
        int t_base_rec, int t_base_gemm, int C)
{
    if (blockIdx.x < REC_BLOCKS) {
        __builtin_amdgcn_s_setprio(1);   // rec is the critical path
        rec_body<LAYER>(blockIdx.x, xg_rec, Whh, outp, state, t_base_rec, C);
    } else {
        gemm_body64<LAYER>(blockIdx.x - REC_BLOCKS, OS, IS, h1,
                           Wih, bih, bhh, xg_next, t_base_gemm, C);
    }
}

// ===================== Path B: original verified fused kernel =====================
template<int LAYER>
__global__ __launch_bounds__(64, 1) void lstm_rec(
        const float* __restrict__ OS, const float* __restrict__ IS,
        const float* __restrict__ Wih, const float* __restrict__ Whh,
        const float* __restrict__ bih, const float* __restrict__ bhh,
        const float* __restrict__ h1in, float* __restrict__ outp)
{
    constexpr int F = (LAYER == 0) ? 32 : 64;
    const int l   = threadIdx.x;
    const int b   = blockIdx.x;
    const int dir = blockIdx.y;
    const int gA  = l;
    const int gB  = 64 + l;

    float wih_a[F], wih_b[F], whh_a[HID], whh_b[HID];
    load_row<F>(wih_a, Wih + ((size_t)dir * 128 + gA) * F);
    load_row<F>(wih_b, Wih + ((size_t)dir * 128 + gB) * F);
    load_row<HID>(whh_a, Whh + ((size_t)dir * 128 + gA) * HID);
    load_row<HID>(whh_b, Whh + ((size_t)dir * 128 + gB) * HID);
    const float biasA = bih[dir * 128 + gA] + bhh[dir * 128 + gA];
    const float biasB = bih[dir * 128 + gB] + bhh[dir * 128 + gB];

    float h[HID];
#pragma unroll
    for (int k = 0; k < HID; ++k) h[k] = 0.f;
    float c = 0.f;
    const bool lo = (l < HID);

    float4 X0[F / 4], X1[F / 4];

    auto load_x = [&](float4* X, int tl) {
        const int te = dir ? (T_LEN - 1 - tl) : tl;
        if constexpr (LAYER == 0) {
            const float4* p0 = reinterpret_cast<const float4*>(OS + ((size_t)b * T_LEN + te) * 16);
            const float4* p1 = reinterpret_cast<const float4*>(IS + ((size_t)b * T_LEN + (T_LEN - 1 - te)) * 16);
#pragma unroll
            for (int i = 0; i < 4; ++i) X[i] = p0[i];
#pragma unroll
            for (int i = 0; i < 4; ++i) X[4 + i] = p1[i];
        } else {
            const float4* p = reinterpret_cast<const float4*>(h1in + ((size_t)te * BATCH + b) * 64);
#pragma unroll
            for (int i = 0; i < F / 4; ++i) X[i] = p[i];
        }
    };

    auto step = [&](int tl, const float4* X) {
        const int te = dir ? (T_LEN - 1 - tl) : tl;
        float accA = biasA, accB = biasB;
#pragma unroll
        for (int i = 0; i < F / 4; ++i) {
            accA = fmaf(X[i].x, wih_a[4*i+0], accA);
            accA = fmaf(X[i].y, wih_a[4*i+1], accA);
            accA = fmaf(X[i].z, wih_a[4*i+2], accA);
            accA = fmaf(X[i].w, wih_a[4*i+3], accA);
            accB = fmaf(X[i].x, wih_b[4*i+0], accB);
            accB = fmaf(X[i].y, wih_b[4*i+1], accB);
            accB = fmaf(X[i].z, wih_b[4*i+2], accB);
            accB = fmaf(X[i].w, wih_b[4*i+3], accB);
        }
#pragma unroll
        for (int k = 0; k < HID; ++k) {
            accA = fmaf(h[k], whh_a[k], accA);
            accB = fmaf(h[k], whh_b[k], accB);
        }
        float sA = frcp(1.f + __expf(-accA));
        float argB = lo ? (-2.f * accB) : (-accB);
        float rB = frcp(1.f + __expf(argB));
        float sB = lo ? fmaf(2.f, rB, -1.f) : rB;
        float sf = __shfl(sA, (l + 32) & 63);
        float so = __shfl(sB, (l + 32) & 63);
        c = fmaf(sf, c, sA * sB);
        float tc = fmaf(2.f, frcp(1.f + __expf(-2.f * c)), -1.f);
        float hj = so * tc;
        if (lo) {
            if constexpr (LAYER == 0)
                outp[((size_t)te * BATCH + b) * 64 + dir * HID + l] = hj;
            else
                outp[((size_t)b * T_LEN + te) * 64 + dir * HID + l] = hj;
        }
#pragma unroll
        for (int k = 0; k < HID; ++k) h[k] = rdlane(hj, k);
    };

    load_x(X0, 0);
#pragma unroll 1
    for (int tt = 0; tt < T_LEN; tt += 2) {
        load_x(X1, tt + 1);
        step(tt, X0);
        int nx = tt + 2; if (nx > T_LEN - 1) nx = T_LEN - 1;
        load_x(X0, nx);
        step(tt + 1, X1);
    }
}

extern "C" void kernel_launch(void* const* d_in, const int* in_sizes, int n_in,
                              void* d_out, int out_size, void* d_ws, size_t ws_size,
                              hipStream_t stream) {
    const float* OS    = (const float*)d_in[0];
    const float* IS    = (const float*)d_in[1];
    const float* W_ih0 = (const float*)d_in[2];
    const float* W_hh0 = (const float*)d_in[3];
    const float* b_ih0 = (const float*)d_in[4];
    const float* b_hh0 = (const float*)d_in[5];
    const float* W_ih1 = (const float*)d_in[6];
    const float* W_hh1 = (const float*)d_in[7];
    const float* b_ih1 = (const float*)d_in[8];
    const float* b_hh1 = (const float*)d_in[9];
    float* out = (float*)d_out;

    const size_t H1_BYTES = (size_t)T_LEN * BATCH * 64 * sizeof(float);   // 134 MiB
    const size_t ST_BYTES = (size_t)512 * 64 * sizeof(float);             // 128 KiB
    const size_t SLACK    = (size_t)PF * BATCH * 128 * sizeof(float);     // 1 MiB

    // pick largest fused chunk C with ping-pong xg buffers
    int C = 0;
    for (int c = 512; c >= 64; c >>= 1) {
        size_t xgc = (size_t)2 * c * BATCH * 128 * sizeof(float);
        if (H1_BYTES + ST_BYTES + 2 * xgc + SLACK <= ws_size) { C = c; break; }
    }

    if (C >= 64) {
        const int NC = T_LEN / C;
        const size_t xgc = (size_t)2 * C * BATCH * 128 * sizeof(float);
        float* h1  = (float*)d_ws;
        float* st  = (float*)((char*)d_ws + H1_BYTES);
        float* xgA = (float*)((char*)d_ws + H1_BYTES + ST_BYTES);
        float* xgB = (float*)((char*)d_ws + H1_BYTES + ST_BYTES + xgc);
        float* xgbuf[2] = { xgA, xgB };

        const int GEMM_BLOCKS = (C / 16) * BATCH * 4;   // 64-thread tiles
        dim3 tb64(64);

        // ---------------- layer 0 ----------------
        hipLaunchKernelGGL((xg_gemm_k<0>), dim3(GEMM_BLOCKS), tb64, 0, stream,
                           OS, IS, (const float*)nullptr, W_ih0, b_ih0, b_hh0,
                           xgbuf[0], 0, C);
        for (int i = 0; i < NC; ++i) {
            const float* xr = xgbuf[i & 1];
            if (i + 1 < NC) {
                hipLaunchKernelGGL((fused_rec_gemm<0>),
                                   dim3(REC_BLOCKS + GEMM_BLOCKS), tb64, 0, stream,
                                   OS, IS, (const float*)nullptr,
                                   W_ih0, b_ih0, b_hh0,
                                   xr, xgbuf[(i + 1) & 1], W_hh0,
                                   h1, st, i * C, (i + 1) * C, C);
            } else {
                hipLaunchKernelGGL((lstm_rec_k<0>), dim3(REC_BLOCKS), tb64, 0, stream,
                                   xr, W_hh0, h1, st, i * C, C);
            }
        }
        // ---------------- layer 1 ----------------
        hipLaunchKernelGGL((xg_gemm_k<1>), dim3(GEMM_BLOCKS), tb64, 0, stream,
                           (const float*)nullptr, (const float*)nullptr, h1,
                           W_ih1, b_ih1, b_hh1, xgbuf[0], 0, C);
        for (int i = 0; i < NC; ++i) {
            const float* xr = xgbuf[i & 1];
            if (i + 1 < NC) {
                hipLaunchKernelGGL((fused_rec_gemm<1>),
                                   dim3(REC_BLOCKS + GEMM_BLOCKS), tb64, 0, stream,
                                   (const float*)nullptr, (const float*)nullptr, h1,
                                   W_ih1, b_ih1, b_hh1,
                                   xr, xgbuf[(i + 1) & 1], W_hh1,
                                   out, st, i * C, (i + 1) * C, C);
            } else {
                hipLaunchKernelGGL((lstm_rec_k<1>), dim3(REC_BLOCKS), tb64, 0, stream,
                                   xr, W_hh1, out, st, i * C, C);
            }
        }
    } else {
        // -------- Path B: original verified fallback --------
        float* h1 = (float*)d_ws;
        dim3 grid(BATCH, 2), block(64);
        hipLaunchKernelGGL((lstm_rec<0>), grid, block, 0, stream,
                           OS, IS, W_ih0, W_hh0, b_ih0, b_hh0, (const float*)nullptr, h1);
        hipLaunchKernelGGL((lstm_rec<1>), grid, block, 0, stream,
                           (const float*)nullptr, (const float*)nullptr,
                           W_ih1, W_hh1, b_ih1, b_hh1, (const float*)h1, out);
    }
}